// Round 3
// baseline (352.921 us; speedup 1.0000x reference)
//
#include <hip/hip_runtime.h>

using f32x4 = __attribute__((ext_vector_type(4))) float;
using s16x8 = __attribute__((ext_vector_type(8))) short;

constexpr int NB   = 16;    // batch
constexpr int CH   = 256;   // channels
constexpr int TT   = 4096;  // time
constexpr int NT   = 64;    // tokens per tile
constexpr int HALO = 8;     // (K-1)*DIL
constexpr int PITCH = 264;  // bf16 elements per LDS row (256 + 8 pad, 16B aligned)
constexpr int XROWS = NT + HALO;  // 72

__device__ __forceinline__ float b2f(ushort u) {
    unsigned v = ((unsigned)u) << 16;
    float f; __builtin_memcpy(&f, &v, 4); return f;
}
__device__ __forceinline__ ushort f2b(float f) {
    unsigned u; __builtin_memcpy(&u, &f, 4);
    u += 0x7FFFu + ((u >> 16) & 1u);   // RNE
    return (ushort)(u >> 16);
}
__device__ __forceinline__ float fast_sigmoid(float x) {
    return __builtin_amdgcn_rcpf(1.f + __expf(-x));
}
__device__ __forceinline__ float fast_tanh(float x) {
    return 2.f * __builtin_amdgcn_rcpf(1.f + __expf(-2.f * x)) - 1.f;
}

// Convert f32 weights to bf16, rearranged:
// W1[m][k]: m<256 filter / m>=256 gate, k = tap*256 + in_ch.
// W2[m][i]: m<256 res / m>=256 skip.
__global__ void prep_w(const float* __restrict__ wf, const float* __restrict__ wg,
                       const float* __restrict__ wr, const float* __restrict__ wsk,
                       ushort* __restrict__ W1, ushort* __restrict__ W2) {
    int idx = blockIdx.x * 256 + threadIdx.x;
    if (idx < 512 * 512) {
        int m = idx >> 9, k = idx & 511, tap = k >> 8, i = k & 255;
        float v = (m < 256) ? wf[((m << 8) + i) * 2 + tap]
                            : wg[(((m - 256) << 8) + i) * 2 + tap];
        W1[idx] = f2b(v);
    } else {
        int j = idx - 512 * 512;
        int m = j >> 8, i = j & 255;
        float v = (m < 256) ? wr[(m << 8) + i] : wsk[((m - 256) << 8) + i];
        W2[j] = f2b(v);
    }
}

// ---------------------------------------------------------------------------
// K1: GEMM1 + tanh*sigmoid gate -> z (bf16, layout [b*T + t][c])
// grid: 2048 blocks = 1024 token-tiles x 2 M-halves; 256 threads (4 waves)
// wave tile: 64 rows (32 filter + 32 gate) x 64 tokens -> acc = 64 floats/lane
// ---------------------------------------------------------------------------
__global__ __launch_bounds__(256, 3)
void gemm1_act(const float* __restrict__ x, const ushort* __restrict__ W1,
               const float* __restrict__ b_filt, const float* __restrict__ b_gate,
               ushort* __restrict__ z) {
    __shared__ __align__(16) ushort ldsx[XROWS * PITCH];   // 38016 B

    const int bx    = blockIdx.x;
    const int tile  = bx >> 1;
    const int mhalf = bx & 1;                 // which 128-channel half of F/G
    const int b  = tile >> 6;
    const int t0 = (tile & 63) << 6;
    const float* X = x + (size_t)b * CH * TT;
    const int tg0 = t0 - HALO;
    const int tid = threadIdx.x;

    // ---- stage x (f32 -> bf16, transposed) into LDS ----
    {
        const int tc   = tid & 15;     // token-chunk (4 tokens)
        const int crow = tid >> 4;     // 0..15
        #pragma unroll
        for (int cg = 0; cg < 16; ++cg) {
            int c  = cg * 16 + crow;
            int tg = tg0 + tc * 4;
            f32x4 v = {0.f, 0.f, 0.f, 0.f};
            if (tg >= 0) v = *(const f32x4*)&X[(size_t)c * TT + tg];
            #pragma unroll
            for (int e = 0; e < 4; ++e)
                ldsx[(tc * 4 + e) * PITCH + c] = f2b(v[e]);
        }
        {   // tail rows 64..71 = tokens t0+56..t0+63 (always in range)
            int c = tid;
            f32x4 v0 = *(const f32x4*)&X[(size_t)c * TT + tg0 + 64];
            f32x4 v1 = *(const f32x4*)&X[(size_t)c * TT + tg0 + 68];
            #pragma unroll
            for (int e = 0; e < 4; ++e) {
                ldsx[(64 + e) * PITCH + c] = f2b(v0[e]);
                ldsx[(68 + e) * PITCH + c] = f2b(v1[e]);
            }
        }
    }
    __syncthreads();

    const int wave = tid >> 6, lane = tid & 63;
    const int l16 = lane & 15, quad = lane >> 4;
    const int mbase = mhalf * 128 + wave * 32;   // filter rows mbase..mbase+31

    f32x4 acc[4][4];   // [mt: 0,1 filter / 2,3 gate][nt token-tile]
    #pragma unroll
    for (int i = 0; i < 4; ++i)
        #pragma unroll
        for (int j = 0; j < 4; ++j) acc[i][j] = (f32x4){0.f, 0.f, 0.f, 0.f};

    #pragma unroll
    for (int kq = 0; kq < 16; ++kq) {
        const int tap = kq >> 3;
        const int col = (kq & 7) * 32 + quad * 8;
        s16x8 bfr[4];
        #pragma unroll
        for (int nt = 0; nt < 4; ++nt)
            bfr[nt] = *(const s16x8*)&ldsx[(nt * 16 + l16 + 8 * tap) * PITCH + col];
        #pragma unroll
        for (int mt = 0; mt < 4; ++mt) {
            int m = (mt < 2 ? mbase + mt * 16 : 256 + mbase + (mt - 2) * 16) + l16;
            s16x8 af = *(const s16x8*)&W1[(size_t)m * 512 + kq * 32 + quad * 8];
            #pragma unroll
            for (int nt = 0; nt < 4; ++nt)
                acc[mt][nt] = __builtin_amdgcn_mfma_f32_16x16x32_bf16(af, bfr[nt], acc[mt][nt], 0, 0, 0);
        }
    }

    // ---- gate -> z global, packed 8B stores ----
    #pragma unroll
    for (int mt = 0; mt < 2; ++mt) {
        const int ch0 = mbase + mt * 16 + quad * 4;      // z channel base
        const f32x4 bf4 = *(const f32x4*)&b_filt[ch0];
        const f32x4 bg4 = *(const f32x4*)&b_gate[ch0];
        #pragma unroll
        for (int nt = 0; nt < 4; ++nt) {
            ushort zr[4];
            #pragma unroll
            for (int r = 0; r < 4; ++r) {
                float fv = acc[mt][nt][r]     + bf4[r];
                float gv = acc[mt + 2][nt][r] + bg4[r];
                zr[r] = f2b(fast_tanh(fv) * fast_sigmoid(gv));
            }
            const size_t zi = ((size_t)b * TT + t0 + nt * 16 + l16) * CH + ch0;
            __builtin_memcpy(&z[zi], zr, 8);
        }
    }
}

// ---------------------------------------------------------------------------
// K2: GEMM2 (+x residual) from z.  No LDS, no barriers.
// grid: 2048 blocks = 1024 token-tiles x 2 (res/skip); 256 threads (4 waves)
// Operands swapped so D = [token][outch] -> dwordx4 epilogue.
// ---------------------------------------------------------------------------
__global__ __launch_bounds__(256, 3)
void gemm2_out(const ushort* __restrict__ z, const ushort* __restrict__ W2,
               const float* __restrict__ x,
               const float* __restrict__ b_res, const float* __restrict__ b_skip,
               float* __restrict__ out) {
    const int bx   = blockIdx.x;
    const int tile = bx >> 1;
    const int half = bx & 1;                  // 0 = res (+x), 1 = skip
    const int b  = tile >> 6;
    const int t0 = (tile & 63) << 6;
    const int tid = threadIdx.x;
    const int wave = tid >> 6, lane = tid & 63;
    const int l16 = lane & 15, quad = lane >> 4;

    const ushort* Z = z + ((size_t)b * TT + t0) * CH;

    f32x4 acc[4][4];   // [nt outch-tile][mt token-tile]
    #pragma unroll
    for (int i = 0; i < 4; ++i)
        #pragma unroll
        for (int j = 0; j < 4; ++j) acc[i][j] = (f32x4){0.f, 0.f, 0.f, 0.f};

    #pragma unroll
    for (int kq = 0; kq < 8; ++kq) {
        const int kcol = kq * 32 + quad * 8;
        s16x8 za[4];
        #pragma unroll
        for (int mt = 0; mt < 4; ++mt)
            za[mt] = *(const s16x8*)&Z[(size_t)(mt * 16 + l16) * CH + kcol];
        #pragma unroll
        for (int nt = 0; nt < 4; ++nt) {
            const int wrow = half * 256 + wave * 64 + nt * 16 + l16;
            s16x8 wb = *(const s16x8*)&W2[(size_t)wrow * 256 + kcol];
            #pragma unroll
            for (int mt = 0; mt < 4; ++mt)
                acc[nt][mt] = __builtin_amdgcn_mfma_f32_16x16x32_bf16(za[mt], wb, acc[nt][mt], 0, 0, 0);
        }
    }

    const size_t OUT1 = (size_t)NB * CH * TT;
    #pragma unroll
    for (int nt = 0; nt < 4; ++nt) {
        const int c = wave * 64 + nt * 16 + l16;
        const float bias = (half ? b_skip : b_res)[c];
        #pragma unroll
        for (int mt = 0; mt < 4; ++mt) {
            const size_t o = ((size_t)(b * CH + c)) * TT + t0 + mt * 16 + quad * 4;
            f32x4 v = acc[nt][mt];
            if (half == 0) {
                f32x4 xv = *(const f32x4*)&x[o];
                #pragma unroll
                for (int r = 0; r < 4; ++r) v[r] += xv[r] + bias;
                *(f32x4*)&out[o] = v;
            } else {
                #pragma unroll
                for (int r = 0; r < 4; ++r) v[r] += bias;
                *(f32x4*)&out[OUT1 + o] = v;
            }
        }
    }
}

// ---------------------------------------------------------------------------
// Fallback (validated round-2 fused kernel) in case d_ws can't hold z.
// ---------------------------------------------------------------------------
__global__ __launch_bounds__(256, 2)
void fused_block(const float* __restrict__ x,
                 const ushort* __restrict__ W1, const ushort* __restrict__ W2,
                 const float* __restrict__ b_filt, const float* __restrict__ b_gate,
                 const float* __restrict__ b_res,  const float* __restrict__ b_skip,
                 float* __restrict__ out) {
    __shared__ __align__(16) ushort ldsx[XROWS * PITCH];

    const int tid = threadIdx.x;
    const int tilesPerB = TT / NT;
    const int b  = blockIdx.x / tilesPerB;
    const int t0 = (blockIdx.x % tilesPerB) * NT;
    const float* X = x + (size_t)b * CH * TT;
    const int tg0 = t0 - HALO;

    {
        const int tc   = tid & 15;
        const int crow = tid >> 4;
        #pragma unroll
        for (int cg = 0; cg < 16; ++cg) {
            int c  = cg * 16 + crow;
            int tg = tg0 + tc * 4;
            f32x4 v = {0.f, 0.f, 0.f, 0.f};
            if (tg >= 0) v = *(const f32x4*)&X[(size_t)c * TT + tg];
            #pragma unroll
            for (int e = 0; e < 4; ++e)
                ldsx[(tc * 4 + e) * PITCH + c] = f2b(v[e]);
        }
        {
            int c = tid;
            f32x4 v0 = *(const f32x4*)&X[(size_t)c * TT + tg0 + 64];
            f32x4 v1 = *(const f32x4*)&X[(size_t)c * TT + tg0 + 68];
            #pragma unroll
            for (int e = 0; e < 4; ++e) {
                ldsx[(64 + e) * PITCH + c] = f2b(v0[e]);
                ldsx[(68 + e) * PITCH + c] = f2b(v1[e]);
            }
        }
    }
    __syncthreads();

    const int wave = tid >> 6, lane = tid & 63;
    const int l16 = lane & 15, quad = lane >> 4;
    const int cb = wave * 64;

    f32x4 acc[8][4];
    #pragma unroll
    for (int i = 0; i < 8; ++i)
        #pragma unroll
        for (int j = 0; j < 4; ++j) acc[i][j] = (f32x4){0.f, 0.f, 0.f, 0.f};

    #pragma unroll
    for (int kq = 0; kq < 16; ++kq) {
        const int tap = kq >> 3, ci = kq & 7;
        const int col = ci * 32 + quad * 8;
        s16x8 bfr[4];
        #pragma unroll
        for (int nt = 0; nt < 4; ++nt)
            bfr[nt] = *(const s16x8*)&ldsx[(nt * 16 + l16 + 8 * tap) * PITCH + col];
        #pragma unroll
        for (int mt = 0; mt < 8; ++mt) {
            int m = (mt < 4 ? cb + mt * 16 : 256 + cb + (mt - 4) * 16) + l16;
            s16x8 af = *(const s16x8*)&W1[(size_t)m * 512 + kq * 32 + quad * 8];
            #pragma unroll
            for (int nt = 0; nt < 4; ++nt)
                acc[mt][nt] = __builtin_amdgcn_mfma_f32_16x16x32_bf16(af, bfr[nt], acc[mt][nt], 0, 0, 0);
        }
    }
    __syncthreads();

    #pragma unroll
    for (int mt = 0; mt < 4; ++mt) {
        const int ch0 = cb + mt * 16 + quad * 4;
        const f32x4 bf4 = *(const f32x4*)&b_filt[ch0];
        const f32x4 bg4 = *(const f32x4*)&b_gate[ch0];
        #pragma unroll
        for (int nt = 0; nt < 4; ++nt) {
            ushort zr[4];
            #pragma unroll
            for (int r = 0; r < 4; ++r) {
                float fv = acc[mt][nt][r]     + bf4[r];
                float gv = acc[mt + 4][nt][r] + bg4[r];
                zr[r] = f2b(fast_tanh(fv) * fast_sigmoid(gv));
            }
            __builtin_memcpy(&ldsx[(nt * 16 + l16) * PITCH + ch0], zr, 8);
        }
    }
    __syncthreads();

    f32x4 acc2[8][4];
    #pragma unroll
    for (int i = 0; i < 8; ++i)
        #pragma unroll
        for (int j = 0; j < 4; ++j) acc2[i][j] = (f32x4){0.f, 0.f, 0.f, 0.f};

    #pragma unroll
    for (int kq = 0; kq < 8; ++kq) {
        const int col = kq * 32 + quad * 8;
        s16x8 bz[4];
        #pragma unroll
        for (int nt = 0; nt < 4; ++nt)
            bz[nt] = *(const s16x8*)&ldsx[(nt * 16 + l16) * PITCH + col];
        #pragma unroll
        for (int mt = 0; mt < 8; ++mt) {
            int m = (mt < 4 ? cb + mt * 16 : 256 + cb + (mt - 4) * 16) + l16;
            s16x8 af = *(const s16x8*)&W2[(size_t)m * 256 + col];
            #pragma unroll
            for (int nt = 0; nt < 4; ++nt)
                acc2[mt][nt] = __builtin_amdgcn_mfma_f32_16x16x32_bf16(af, bz[nt], acc2[mt][nt], 0, 0, 0);
        }
    }

    const size_t OUT1 = (size_t)NB * CH * TT;
    #pragma unroll
    for (int mt = 0; mt < 4; ++mt) {
        const int ch0 = cb + mt * 16 + quad * 4;
        const f32x4 br4 = *(const f32x4*)&b_res[ch0];
        const f32x4 bs4 = *(const f32x4*)&b_skip[ch0];
        #pragma unroll
        for (int nt = 0; nt < 4; ++nt) {
            const int tok = nt * 16 + l16;
            const int tg  = t0 + tok;
            #pragma unroll
            for (int r = 0; r < 4; ++r) {
                const int ch = ch0 + r;
                const size_t o = ((size_t)(b * CH + ch)) * TT + tg;
                float xv = X[(size_t)ch * TT + tg];
                out[o]        = xv + acc2[mt][nt][r] + br4[r];
                out[OUT1 + o] = acc2[mt + 4][nt][r] + bs4[r];
            }
        }
    }
}

extern "C" void kernel_launch(void* const* d_in, const int* in_sizes, int n_in,
                              void* d_out, int out_size, void* d_ws, size_t ws_size,
                              hipStream_t stream) {
    const float* x   = (const float*)d_in[0];
    const float* wf  = (const float*)d_in[1];
    const float* bfi = (const float*)d_in[2];
    const float* wg  = (const float*)d_in[3];
    const float* bg  = (const float*)d_in[4];
    const float* wr  = (const float*)d_in[5];
    const float* br  = (const float*)d_in[6];
    const float* wsk = (const float*)d_in[7];
    const float* bs  = (const float*)d_in[8];

    ushort* W1 = (ushort*)d_ws;                  // 512*512 bf16  (512 KB)
    ushort* W2 = W1 + 512 * 512;                 // 512*256 bf16  (256 KB)
    ushort* z  = W2 + 512 * 256;                 // 16*4096*256 bf16 (33.5 MB)

    const size_t needed = (size_t)(512 * 512 + 512 * 256) * 2
                        + (size_t)NB * TT * CH * 2;

    prep_w<<<1536, 256, 0, stream>>>(wf, wg, wr, wsk, W1, W2);

    if (ws_size >= needed) {
        gemm1_act<<<2048, 256, 0, stream>>>(x, W1, bfi, bg, z);
        gemm2_out<<<2048, 256, 0, stream>>>(z, W2, x, br, bs, (float*)d_out);
    } else {
        fused_block<<<NB * (TT / NT), 256, 0, stream>>>(x, W1, W2, bfi, bg, br, bs,
                                                        (float*)d_out);
    }
}

// Round 4
// 346.885 us; speedup vs baseline: 1.0174x; 1.0174x over previous
//
#include <hip/hip_runtime.h>

using f32x4 = __attribute__((ext_vector_type(4))) float;
using s16x8 = __attribute__((ext_vector_type(8))) short;

constexpr int NB   = 16;    // batch
constexpr int CH   = 256;   // channels
constexpr int TT   = 4096;  // time
constexpr int NT   = 64;    // tokens per tile
constexpr int HALO = 8;     // (K-1)*DIL
constexpr int PITCH  = 272; // x-tile row pitch (u16): 136 dwords == 8 mod 32 -> conflict-free b128
constexpr int PITCHZ = 272; // z-tile row pitch (u16)
constexpr int XROWS = NT + HALO;  // 72

__device__ __forceinline__ ushort f2b(float f) {
    unsigned u; __builtin_memcpy(&u, &f, 4);
    u += 0x7FFFu + ((u >> 16) & 1u);   // RNE
    return (ushort)(u >> 16);
}
__device__ __forceinline__ float fast_sigmoid(float x) {
    return __builtin_amdgcn_rcpf(1.f + __expf(-x));
}
__device__ __forceinline__ float fast_tanh(float x) {
    return 2.f * __builtin_amdgcn_rcpf(1.f + __expf(-2.f * x)) - 1.f;
}

// W1[m][k]: m<256 filter / m>=256 gate, k = tap*256 + in_ch.  W2[m][i]: m<256 res / m>=256 skip.
__global__ void prep_w(const float* __restrict__ wf, const float* __restrict__ wg,
                       const float* __restrict__ wr, const float* __restrict__ wsk,
                       ushort* __restrict__ W1, ushort* __restrict__ W2) {
    int idx = blockIdx.x * 256 + threadIdx.x;
    if (idx < 512 * 512) {
        int m = idx >> 9, k = idx & 511, tap = k >> 8, i = k & 255;
        float v = (m < 256) ? wf[((m << 8) + i) * 2 + tap]
                            : wg[(((m - 256) << 8) + i) * 2 + tap];
        W1[idx] = f2b(v);
    } else {
        int j = idx - 512 * 512;
        int m = j >> 8, i = j & 255;
        float v = (m < 256) ? wr[(m << 8) + i] : wsk[((m - 256) << 8) + i];
        W2[j] = f2b(v);
    }
}

// ---------------------------------------------------------------------------
// K1: GEMM1 + gate -> z.  Rolling register prefetch of W1 fragments:
// double-buffered 4-kq groups (16 frags = 64 VGPRs per buffer); group 0 is
// issued BEFORE the staging barrier so it overlaps x-staging.
// ---------------------------------------------------------------------------
__global__ __launch_bounds__(256, 2)
void gemm1_act(const float* __restrict__ x, const ushort* __restrict__ W1,
               const float* __restrict__ b_filt, const float* __restrict__ b_gate,
               ushort* __restrict__ z) {
    __shared__ __align__(16) ushort ldsx[XROWS * PITCH];   // 39168 B

    const int bx    = blockIdx.x;
    const int tile  = bx >> 1;
    const int mhalf = bx & 1;
    const int b  = tile >> 6;
    const int t0 = (tile & 63) << 6;
    const float* X = x + (size_t)b * CH * TT;
    const int tg0 = t0 - HALO;
    const int tid = threadIdx.x;
    const int wave = tid >> 6, lane = tid & 63;
    const int l16 = lane & 15, quad = lane >> 4;
    const int mbase = mhalf * 128 + wave * 32;

    // per-mt W1 row pointers (row m + this lane's k-phase)
    const ushort* Wrow[4];
    #pragma unroll
    for (int mt = 0; mt < 4; ++mt) {
        int m = (mt < 2 ? mbase + mt * 16 : 256 + mbase + (mt - 2) * 16) + l16;
        Wrow[mt] = W1 + (size_t)m * 512 + quad * 8;
    }

    // prefetch group 0 (kq 0..3) before staging
    s16x8 Abuf[2][16];
    #pragma unroll
    for (int k4 = 0; k4 < 4; ++k4)
        #pragma unroll
        for (int mt = 0; mt < 4; ++mt)
            Abuf[0][k4 * 4 + mt] = *(const s16x8*)(Wrow[mt] + k4 * 32);

    // ---- stage x (f32 -> bf16, transposed) into LDS ----
    {
        const int tc   = tid & 15;     // token-chunk (4 tokens)
        const int crow = tid >> 4;     // 0..15
        #pragma unroll
        for (int cg = 0; cg < 16; ++cg) {
            int c  = cg * 16 + crow;
            int tg = tg0 + tc * 4;
            f32x4 v = {0.f, 0.f, 0.f, 0.f};
            if (tg >= 0) v = *(const f32x4*)&X[(size_t)c * TT + tg];
            #pragma unroll
            for (int e = 0; e < 4; ++e)
                ldsx[(tc * 4 + e) * PITCH + c] = f2b(v[e]);
        }
        {   // tail rows 64..71 = tokens t0+56..t0+63 (always in range)
            int c = tid;
            f32x4 v0 = *(const f32x4*)&X[(size_t)c * TT + tg0 + 64];
            f32x4 v1 = *(const f32x4*)&X[(size_t)c * TT + tg0 + 68];
            #pragma unroll
            for (int e = 0; e < 4; ++e) {
                ldsx[(64 + e) * PITCH + c] = f2b(v0[e]);
                ldsx[(68 + e) * PITCH + c] = f2b(v1[e]);
            }
        }
    }
    __syncthreads();

    f32x4 acc[4][4];   // [mt: 0,1 filter / 2,3 gate][nt]
    #pragma unroll
    for (int i = 0; i < 4; ++i)
        #pragma unroll
        for (int j = 0; j < 4; ++j) acc[i][j] = (f32x4){0.f, 0.f, 0.f, 0.f};

    #pragma unroll
    for (int g = 0; g < 4; ++g) {            // groups of 4 kq
        if (g < 3) {                         // prefetch next group
            #pragma unroll
            for (int k4 = 0; k4 < 4; ++k4)
                #pragma unroll
                for (int mt = 0; mt < 4; ++mt)
                    Abuf[(g + 1) & 1][k4 * 4 + mt] =
                        *(const s16x8*)(Wrow[mt] + (g * 4 + 4 + k4) * 32);
        }
        #pragma unroll
        for (int k4 = 0; k4 < 4; ++k4) {
            const int kq  = g * 4 + k4;
            const int tap = kq >> 3;
            const int col = (kq & 7) * 32 + quad * 8;
            s16x8 bfr[4];
            #pragma unroll
            for (int nt = 0; nt < 4; ++nt)
                bfr[nt] = *(const s16x8*)&ldsx[(nt * 16 + l16 + 8 * tap) * PITCH + col];
            #pragma unroll
            for (int mt = 0; mt < 4; ++mt)
                #pragma unroll
                for (int nt = 0; nt < 4; ++nt)
                    acc[mt][nt] = __builtin_amdgcn_mfma_f32_16x16x32_bf16(
                        Abuf[g & 1][k4 * 4 + mt], bfr[nt], acc[mt][nt], 0, 0, 0);
        }
    }

    // ---- gate -> z global, packed 8B stores ----
    #pragma unroll
    for (int mt = 0; mt < 2; ++mt) {
        const int ch0 = mbase + mt * 16 + quad * 4;
        const f32x4 bf4 = *(const f32x4*)&b_filt[ch0];
        const f32x4 bg4 = *(const f32x4*)&b_gate[ch0];
        #pragma unroll
        for (int nt = 0; nt < 4; ++nt) {
            ushort zr[4];
            #pragma unroll
            for (int r = 0; r < 4; ++r) {
                float fv = acc[mt][nt][r]     + bf4[r];
                float gv = acc[mt + 2][nt][r] + bg4[r];
                zr[r] = f2b(fast_tanh(fv) * fast_sigmoid(gv));
            }
            const size_t zi = ((size_t)b * TT + t0 + nt * 16 + l16) * CH + ch0;
            __builtin_memcpy(&z[zi], zr, 8);
        }
    }
}

// ---------------------------------------------------------------------------
// K2: GEMM2 (+x residual).  z tile staged in LDS (pitch 272, conflict-free);
// W2 fragments rolling-prefetched in 2-kq groups (issued pre-barrier first).
// ---------------------------------------------------------------------------
__global__ __launch_bounds__(256, 3)
void gemm2_out(const ushort* __restrict__ z, const ushort* __restrict__ W2,
               const float* __restrict__ x,
               const float* __restrict__ b_res, const float* __restrict__ b_skip,
               float* __restrict__ out) {
    __shared__ __align__(16) ushort ldsz[NT * PITCHZ];   // 34816 B

    const int bx   = blockIdx.x;
    const int tile = bx >> 1;
    const int half = bx & 1;                  // 0 = res (+x), 1 = skip
    const int b  = tile >> 6;
    const int t0 = (tile & 63) << 6;
    const int tid = threadIdx.x;
    const int wave = tid >> 6, lane = tid & 63;
    const int l16 = lane & 15, quad = lane >> 4;

    const ushort* W2row[4];
    #pragma unroll
    for (int nt = 0; nt < 4; ++nt) {
        int wrow = half * 256 + wave * 64 + nt * 16 + l16;
        W2row[nt] = W2 + (size_t)wrow * 256 + quad * 8;
    }

    // prefetch group 0 (kq 0,1) before staging
    s16x8 Bbuf[2][8];
    #pragma unroll
    for (int k2 = 0; k2 < 2; ++k2)
        #pragma unroll
        for (int nt = 0; nt < 4; ++nt)
            Bbuf[0][k2 * 4 + nt] = *(const s16x8*)(W2row[nt] + k2 * 32);

    // ---- stage z tile (already [t][c]) into pitched LDS ----
    {
        const ushort* Zt = z + ((size_t)b * TT + t0) * CH;
        const int row = tid >> 2, q4 = tid & 3;
        #pragma unroll
        for (int i = 0; i < 8; ++i) {
            uint4 v = *(const uint4*)&Zt[(size_t)row * CH + q4 * 64 + i * 8];
            *(uint4*)&ldsz[row * PITCHZ + q4 * 64 + i * 8] = v;
        }
    }
    __syncthreads();

    f32x4 acc[4][4];   // [nt outch-tile][mt token-tile]
    #pragma unroll
    for (int i = 0; i < 4; ++i)
        #pragma unroll
        for (int j = 0; j < 4; ++j) acc[i][j] = (f32x4){0.f, 0.f, 0.f, 0.f};

    #pragma unroll
    for (int g = 0; g < 4; ++g) {            // groups of 2 kq
        if (g < 3) {
            #pragma unroll
            for (int k2 = 0; k2 < 2; ++k2)
                #pragma unroll
                for (int nt = 0; nt < 4; ++nt)
                    Bbuf[(g + 1) & 1][k2 * 4 + nt] =
                        *(const s16x8*)(W2row[nt] + (g * 2 + 2 + k2) * 32);
        }
        #pragma unroll
        for (int k2 = 0; k2 < 2; ++k2) {
            const int kq = g * 2 + k2;
            const int kcol = kq * 32 + quad * 8;
            s16x8 za[4];
            #pragma unroll
            for (int mt = 0; mt < 4; ++mt)
                za[mt] = *(const s16x8*)&ldsz[(mt * 16 + l16) * PITCHZ + kcol];
            #pragma unroll
            for (int nt = 0; nt < 4; ++nt)
                #pragma unroll
                for (int mt = 0; mt < 4; ++mt)
                    acc[nt][mt] = __builtin_amdgcn_mfma_f32_16x16x32_bf16(
                        za[mt], Bbuf[g & 1][k2 * 4 + nt], acc[nt][mt], 0, 0, 0);
        }
    }

    const size_t OUT1 = (size_t)NB * CH * TT;
    #pragma unroll
    for (int nt = 0; nt < 4; ++nt) {
        const int c = wave * 64 + nt * 16 + l16;
        const float bias = (half ? b_skip : b_res)[c];
        #pragma unroll
        for (int mt = 0; mt < 4; ++mt) {
            const size_t o = ((size_t)(b * CH + c)) * TT + t0 + mt * 16 + quad * 4;
            f32x4 v = acc[nt][mt];
            if (half == 0) {
                f32x4 xv = *(const f32x4*)&x[o];
                #pragma unroll
                for (int r = 0; r < 4; ++r) v[r] += xv[r] + bias;
                *(f32x4*)&out[o] = v;
            } else {
                #pragma unroll
                for (int r = 0; r < 4; ++r) v[r] += bias;
                *(f32x4*)&out[OUT1 + o] = v;
            }
        }
    }
}

// ---------------------------------------------------------------------------
// Fallback (validated round-2 fused kernel) in case d_ws can't hold z.
// ---------------------------------------------------------------------------
__global__ __launch_bounds__(256, 2)
void fused_block(const float* __restrict__ x,
                 const ushort* __restrict__ W1, const ushort* __restrict__ W2,
                 const float* __restrict__ b_filt, const float* __restrict__ b_gate,
                 const float* __restrict__ b_res,  const float* __restrict__ b_skip,
                 float* __restrict__ out) {
    __shared__ __align__(16) ushort ldsx[XROWS * PITCH];

    const int tid = threadIdx.x;
    const int tilesPerB = TT / NT;
    const int b  = blockIdx.x / tilesPerB;
    const int t0 = (blockIdx.x % tilesPerB) * NT;
    const float* X = x + (size_t)b * CH * TT;
    const int tg0 = t0 - HALO;

    {
        const int tc   = tid & 15;
        const int crow = tid >> 4;
        #pragma unroll
        for (int cg = 0; cg < 16; ++cg) {
            int c  = cg * 16 + crow;
            int tg = tg0 + tc * 4;
            f32x4 v = {0.f, 0.f, 0.f, 0.f};
            if (tg >= 0) v = *(const f32x4*)&X[(size_t)c * TT + tg];
            #pragma unroll
            for (int e = 0; e < 4; ++e)
                ldsx[(tc * 4 + e) * PITCH + c] = f2b(v[e]);
        }
        {
            int c = tid;
            f32x4 v0 = *(const f32x4*)&X[(size_t)c * TT + tg0 + 64];
            f32x4 v1 = *(const f32x4*)&X[(size_t)c * TT + tg0 + 68];
            #pragma unroll
            for (int e = 0; e < 4; ++e) {
                ldsx[(64 + e) * PITCH + c] = f2b(v0[e]);
                ldsx[(68 + e) * PITCH + c] = f2b(v1[e]);
            }
        }
    }
    __syncthreads();

    const int wave = tid >> 6, lane = tid & 63;
    const int l16 = lane & 15, quad = lane >> 4;
    const int cb = wave * 64;

    f32x4 acc[8][4];
    #pragma unroll
    for (int i = 0; i < 8; ++i)
        #pragma unroll
        for (int j = 0; j < 4; ++j) acc[i][j] = (f32x4){0.f, 0.f, 0.f, 0.f};

    #pragma unroll
    for (int kq = 0; kq < 16; ++kq) {
        const int tap = kq >> 3, ci = kq & 7;
        const int col = ci * 32 + quad * 8;
        s16x8 bfr[4];
        #pragma unroll
        for (int nt = 0; nt < 4; ++nt)
            bfr[nt] = *(const s16x8*)&ldsx[(nt * 16 + l16 + 8 * tap) * PITCH + col];
        #pragma unroll
        for (int mt = 0; mt < 8; ++mt) {
            int m = (mt < 4 ? cb + mt * 16 : 256 + cb + (mt - 4) * 16) + l16;
            s16x8 af = *(const s16x8*)&W1[(size_t)m * 512 + kq * 32 + quad * 8];
            #pragma unroll
            for (int nt = 0; nt < 4; ++nt)
                acc[mt][nt] = __builtin_amdgcn_mfma_f32_16x16x32_bf16(af, bfr[nt], acc[mt][nt], 0, 0, 0);
        }
    }
    __syncthreads();

    #pragma unroll
    for (int mt = 0; mt < 4; ++mt) {
        const int ch0 = cb + mt * 16 + quad * 4;
        const f32x4 bf4 = *(const f32x4*)&b_filt[ch0];
        const f32x4 bg4 = *(const f32x4*)&b_gate[ch0];
        #pragma unroll
        for (int nt = 0; nt < 4; ++nt) {
            ushort zr[4];
            #pragma unroll
            for (int r = 0; r < 4; ++r) {
                float fv = acc[mt][nt][r]     + bf4[r];
                float gv = acc[mt + 4][nt][r] + bg4[r];
                zr[r] = f2b(fast_tanh(fv) * fast_sigmoid(gv));
            }
            __builtin_memcpy(&ldsx[(nt * 16 + l16) * PITCH + ch0], zr, 8);
        }
    }
    __syncthreads();

    f32x4 acc2[8][4];
    #pragma unroll
    for (int i = 0; i < 8; ++i)
        #pragma unroll
        for (int j = 0; j < 4; ++j) acc2[i][j] = (f32x4){0.f, 0.f, 0.f, 0.f};

    #pragma unroll
    for (int kq = 0; kq < 8; ++kq) {
        const int col = kq * 32 + quad * 8;
        s16x8 bz[4];
        #pragma unroll
        for (int nt = 0; nt < 4; ++nt)
            bz[nt] = *(const s16x8*)&ldsx[(nt * 16 + l16) * PITCH + col];
        #pragma unroll
        for (int mt = 0; mt < 8; ++mt) {
            int m = (mt < 4 ? cb + mt * 16 : 256 + cb + (mt - 4) * 16) + l16;
            s16x8 af = *(const s16x8*)&W2[(size_t)m * 256 + col];
            #pragma unroll
            for (int nt = 0; nt < 4; ++nt)
                acc2[mt][nt] = __builtin_amdgcn_mfma_f32_16x16x32_bf16(af, bz[nt], acc2[mt][nt], 0, 0, 0);
        }
    }

    const size_t OUT1 = (size_t)NB * CH * TT;
    #pragma unroll
    for (int mt = 0; mt < 4; ++mt) {
        const int ch0 = cb + mt * 16 + quad * 4;
        const f32x4 br4 = *(const f32x4*)&b_res[ch0];
        const f32x4 bs4 = *(const f32x4*)&b_skip[ch0];
        #pragma unroll
        for (int nt = 0; nt < 4; ++nt) {
            const int tok = nt * 16 + l16;
            const int tg  = t0 + tok;
            #pragma unroll
            for (int r = 0; r < 4; ++r) {
                const int ch = ch0 + r;
                const size_t o = ((size_t)(b * CH + ch)) * TT + tg;
                float xv = X[(size_t)ch * TT + tg];
                out[o]        = xv + acc2[mt][nt][r] + br4[r];
                out[OUT1 + o] = acc2[mt + 4][nt][r] + bs4[r];
            }
        }
    }
}

extern "C" void kernel_launch(void* const* d_in, const int* in_sizes, int n_in,
                              void* d_out, int out_size, void* d_ws, size_t ws_size,
                              hipStream_t stream) {
    const float* x   = (const float*)d_in[0];
    const float* wf  = (const float*)d_in[1];
    const float* bfi = (const float*)d_in[2];
    const float* wg  = (const float*)d_in[3];
    const float* bg  = (const float*)d_in[4];
    const float* wr  = (const float*)d_in[5];
    const float* br  = (const float*)d_in[6];
    const float* wsk = (const float*)d_in[7];
    const float* bs  = (const float*)d_in[8];

    ushort* W1 = (ushort*)d_ws;                  // 512*512 bf16  (512 KB)
    ushort* W2 = W1 + 512 * 512;                 // 512*256 bf16  (256 KB)
    ushort* z  = W2 + 512 * 256;                 // 16*4096*256 bf16 (33.5 MB)

    const size_t needed = (size_t)(512 * 512 + 512 * 256) * 2
                        + (size_t)NB * TT * CH * 2;

    prep_w<<<1536, 256, 0, stream>>>(wf, wg, wr, wsk, W1, W2);

    if (ws_size >= needed) {
        gemm1_act<<<2048, 256, 0, stream>>>(x, W1, bfi, bg, z);
        gemm2_out<<<2048, 256, 0, stream>>>(z, W2, x, br, bs, (float*)d_out);
    } else {
        fused_block<<<NB * (TT / NT), 256, 0, stream>>>(x, W1, W2, bfi, bg, br, bs,
                                                        (float*)d_out);
    }
}